// Round 4
// baseline (995.253 us; speedup 1.0000x reference)
//
#include <hip/hip_runtime.h>
#include <hip/hip_bf16.h>

// Problem dims
#define B_SZ   8192
#define IN_SZ  1024
#define H1_SZ  2048
#define H2_SZ  2048
#define OUT_SZ 1024
#define NP     8

typedef __bf16 bf16x8 __attribute__((ext_vector_type(8)));
typedef float  f32x4  __attribute__((ext_vector_type(4)));

__device__ __forceinline__ void async_ld16(const void* g, void* l) {
    __builtin_amdgcn_global_load_lds(
        (const __attribute__((address_space(1))) unsigned int*)g,
        (__attribute__((address_space(3))) unsigned int*)l,
        16, 0, 0);
}

// ---------------------------------------------------------------------------
// Unified prep kernel: 3 weight transposes (f32 [K][N] -> bf16 [N][K]) + x cast,
// one dispatch (flat block ranges) instead of 4 launches.
// ---------------------------------------------------------------------------
__device__ __forceinline__ void transpose_body(float (*tile)[33],
                                               const float* __restrict__ in,
                                               __hip_bfloat16* __restrict__ out,
                                               int K, int N, int bx, int by) {
    int n0 = bx * 32, k0 = by * 32;
    int tx = threadIdx.x, ty = threadIdx.y;  // 32 x 8
#pragma unroll
    for (int j = 0; j < 4; ++j)
        tile[ty + j * 8][tx] = in[(size_t)(k0 + ty + j * 8) * N + (n0 + tx)];
    __syncthreads();
    const int kk = (tx & 15) * 2;
#pragma unroll
    for (int j = 0; j < 2; ++j) {
        int nn = ty + j * 8 + (tx >> 4) * 16;
        __hip_bfloat16 t2[2] = {__float2bfloat16(tile[kk][nn]),
                                __float2bfloat16(tile[kk + 1][nn])};
        unsigned int u;
        __builtin_memcpy(&u, t2, 4);
        *(unsigned int*)(out + (size_t)(n0 + nn) * K + (k0 + kk)) = u;
    }
}

__global__ void prep_k(const float* __restrict__ W1, const float* __restrict__ W2,
                       const float* __restrict__ Wc, const float* __restrict__ x,
                       __hip_bfloat16* __restrict__ W1t, __hip_bfloat16* __restrict__ W2t,
                       __hip_bfloat16* __restrict__ Wct, __hip_bfloat16* __restrict__ xbf) {
    __shared__ float tile[32][33];
    int id = blockIdx.x;
    const int nA = (H1_SZ / 32) * ((NP * IN_SZ) / 32);   // 16384
    const int nB = (H2_SZ / 32) * ((NP * H1_SZ) / 32);   // 32768
    const int nC = (OUT_SZ / 32) * (H2_SZ / 32);         // 2048
    if (id < nA) {
        transpose_body(tile, W1, W1t, NP * IN_SZ, H1_SZ, id % (H1_SZ / 32), id / (H1_SZ / 32));
        return;
    }
    id -= nA;
    if (id < nB) {
        transpose_body(tile, W2, W2t, NP * H1_SZ, H2_SZ, id % (H2_SZ / 32), id / (H2_SZ / 32));
        return;
    }
    id -= nB;
    if (id < nC) {
        transpose_body(tile, Wc, Wct, H2_SZ, OUT_SZ, id % (OUT_SZ / 32), id / (OUT_SZ / 32));
        return;
    }
    id -= nC;
    {   // cast x -> bf16, 8 elems/thread
        int t = threadIdx.y * 32 + threadIdx.x;
        size_t i = ((size_t)id * 256 + t) * 8;
        float4 f0 = *(const float4*)(x + i);
        float4 f1 = *(const float4*)(x + i + 4);
        __hip_bfloat16 tt[8] = {
            __float2bfloat16(f0.x), __float2bfloat16(f0.y),
            __float2bfloat16(f0.z), __float2bfloat16(f0.w),
            __float2bfloat16(f1.x), __float2bfloat16(f1.y),
            __float2bfloat16(f1.z), __float2bfloat16(f1.w)};
        uint4 u4;
        __builtin_memcpy(&u4, tt, 16);
        *(uint4*)(xbf + i) = u4;
    }
}

// probs[b,:] = softmax(in[b,:] @ S + sb)   — one wave per row.
// Also writes ratT[p][b]: running-rescale factors for the fused GEMM:
//   ratT[p<7] = v[p]/v[p+1]  (unnormalized numerators; normalization cancels)
//   ratT[7]   = probs[b,7]   (final normalize-and-scale)
template <typename T>
__global__ void selector_k(const T* __restrict__ in, const float* __restrict__ S,
                           const float* __restrict__ sb, float* __restrict__ probs,
                           float* __restrict__ ratT, int K) {
    int row  = blockIdx.x * blockDim.y + threadIdx.y;
    int lane = threadIdx.x;
    float acc[NP];
#pragma unroll
    for (int p = 0; p < NP; ++p) acc[p] = 0.f;
    const T* xr = in + (size_t)row * K;
    for (int k = lane; k < K; k += 64) {
        float xv;
        if constexpr (sizeof(T) == 2) xv = __bfloat162float(xr[k]);
        else                          xv = (float)xr[k];
        const float* sr = S + (size_t)k * NP;
#pragma unroll
        for (int p = 0; p < NP; ++p) acc[p] += xv * sr[p];
    }
#pragma unroll
    for (int p = 0; p < NP; ++p)
#pragma unroll
        for (int off = 32; off > 0; off >>= 1)
            acc[p] += __shfl_down(acc[p], off, 64);
    if (lane == 0) {
        float v[NP], m = -1e30f;
#pragma unroll
        for (int p = 0; p < NP; ++p) { v[p] = acc[p] + sb[p]; m = fmaxf(m, v[p]); }
        float s = 0.f;
#pragma unroll
        for (int p = 0; p < NP; ++p) { v[p] = expf(v[p] - m); s += v[p]; }
        float inv = 1.f / s;
#pragma unroll
        for (int p = 0; p < NP; ++p) probs[(size_t)row * NP + p] = v[p] * inv;
#pragma unroll
        for (int p = 0; p < NP - 1; ++p) ratT[(size_t)p * B_SZ + row] = v[p] / v[p + 1];
        ratT[(size_t)(NP - 1) * B_SZ + row] = v[NP - 1] * inv;
    }
}

// ---------------------------------------------------------------------------
// FUSED DRN layer GEMM: C = relu(Σ_p probs[b,p]·(x @ W[p]) + Σ_p probs·bexp[p,:])
// 256x256 tile, 8 waves (2Mx4N), BK=64, 8-phase counted-vmcnt schedule.
// Staging/confirm schedule = R2's verified one:
//   ph1-2 A(T+1)->b1, ph3-4 B(T+2)->b0, ph5-6 A(T+2)->b0, ph7-8 B(T+3)->b1;
//   vmcnt(4) at ph4 (confirms tile T+1) and ph8 (confirms tile T+2).
// Phase MFMA grouping by (m-half, k-half): uniform ds_read counts (8/8/4/4 per
// tile) instead of a 12-read ph1 burst; all 16 MFMAs within a phase are
// independent (k0/k1 dependent pairs land in different phases). Per-acc
// accumulation order unchanged -> bitwise identical to R2.
// ds_reads go through 8 precomputed per-lane base pointers (buf x k-half), so
// every read is one ds_read_b128 with a constant immediate offset (no per-read
// XOR/add VALU).
// probs folded via telescoping acc rescale at segment boundaries (ratT).
// ---------------------------------------------------------------------------
template <int TPS>
__global__ __launch_bounds__(512, 2)
void drn_gemm8_k(const __hip_bfloat16* __restrict__ A, const __hip_bfloat16* __restrict__ Wt,
                 int N, int K, int Kin, const float* __restrict__ ratT,
                 const float* __restrict__ probs, const float* __restrict__ bexp,
                 __hip_bfloat16* __restrict__ C) {
    __shared__ alignas(16) char smem[131072];

    const int tid  = threadIdx.x;
    const int wid  = tid >> 6, lane = tid & 63;
    const int quad = lane >> 4, l16 = lane & 15;
    const int wr = wid >> 2, wc = wid & 3;          // 2 x 4 wave grid

    // XCD-aware swizzle: 8 XCDs get contiguous chunks, n-fastest within.
    const int g   = blockIdx.x;
    const int cpx = gridDim.x >> 3;
    const int wg  = (g & 7) * cpx + (g >> 3);
    const int nbn = N >> 8;
    const int mb  = wg / nbn, nb = wg % nbn;
    const int m0  = mb * 256, n0 = nb * 256;

    // ---- staging addressing (global side carries the chunk swizzle)
    const int arow = tid >> 3;                        // 0..63
    const int gsw  = ((tid & 7) ^ (arow & 7)) << 3;   // swizzled 8-elem chunk
    const __hip_bfloat16* Ag = A  + (size_t)(m0 + arow) * Kin + gsw;
    const __hip_bfloat16* Bg = Wt + (size_t)(n0 + arow) * K + gsw;
    const size_t r64a = (size_t)64 * Kin;
    const size_t r64b = (size_t)64 * K;
    char* aDst = smem + wid * 1024;                   // + lane*16 by HW
    char* bDst = smem + 65536 + wid * 1024;

#define STG_A(dbuf, ksrc, h) do {                                              \
    const __hip_bfloat16* s_ = Ag + (((ksrc) & (TPS - 1)) * 64) + (size_t)(2*(h)) * r64a; \
    char* d_ = aDst + (dbuf) * 32768 + (h) * 16384;                            \
    async_ld16(s_,        d_);                                                 \
    async_ld16(s_ + r64a, d_ + 8192); } while (0)
#define STG_B(dbuf, ksrc, h) do {                                              \
    const __hip_bfloat16* s_ = Bg + ((size_t)(ksrc) * 64) + (size_t)(2*(h)) * r64b; \
    char* d_ = bDst + (dbuf) * 32768 + (h) * 16384;                            \
    async_ld16(s_,        d_);                                                 \
    async_ld16(s_ + r64b, d_ + 8192); } while (0)

    // ---- ds_read base pointers: [dbuf][k-half], every read = base + const imm
    const int csw   = (quad ^ (l16 & 7)) << 4;
    const int abase = (wr * 128 + l16) * 128 + csw;
    const int bbase = 65536 + (wc * 64 + l16) * 128 + csw;
    const char* aB[2][2] = {{smem + abase,         smem + (abase ^ 64)},
                            {smem + 32768 + abase, smem + 32768 + (abase ^ 64)}};
    const char* bB[2][2] = {{smem + bbase,         smem + (bbase ^ 64)},
                            {smem + 32768 + bbase, smem + 32768 + (bbase ^ 64)}};

#define LD_A4(d, mh, kh)                                                        \
    af[0] = *(const bf16x8*)(aB[d][kh] + ((mh) * 4 + 0) * 2048);                \
    af[1] = *(const bf16x8*)(aB[d][kh] + ((mh) * 4 + 1) * 2048);                \
    af[2] = *(const bf16x8*)(aB[d][kh] + ((mh) * 4 + 2) * 2048);                \
    af[3] = *(const bf16x8*)(aB[d][kh] + ((mh) * 4 + 3) * 2048)
#define LD_B4(d, kh)                                                            \
    bfr[0][kh] = *(const bf16x8*)(bB[d][kh] + 0 * 2048);                        \
    bfr[1][kh] = *(const bf16x8*)(bB[d][kh] + 1 * 2048);                        \
    bfr[2][kh] = *(const bf16x8*)(bB[d][kh] + 2 * 2048);                        \
    bfr[3][kh] = *(const bf16x8*)(bB[d][kh] + 3 * 2048)

#define BAR()                                              \
    __builtin_amdgcn_s_barrier();                          \
    __builtin_amdgcn_sched_barrier(0)

#define LGKM0()                                            \
    asm volatile("s_waitcnt lgkmcnt(0)" ::: "memory");     \
    __builtin_amdgcn_sched_barrier(0)

#define VMW(n) asm volatile("s_waitcnt vmcnt(" #n ")" ::: "memory")

#define MF(mh, kh) do {                                    \
    __builtin_amdgcn_s_setprio(1);                         \
    _Pragma("unroll")                                      \
    for (int ml = 0; ml < 4; ++ml)                         \
      _Pragma("unroll")                                    \
      for (int n_ = 0; n_ < 4; ++n_)                       \
        acc[(mh) * 4 + ml][n_] = __builtin_amdgcn_mfma_f32_16x16x32_bf16( \
            af[ml], bfr[n_][kh], acc[(mh) * 4 + ml][n_], 0, 0, 0);        \
    __builtin_amdgcn_s_setprio(0); } while (0)

    f32x4 zero = {0.f, 0.f, 0.f, 0.f};
    f32x4 acc[8][4];
#pragma unroll
    for (int m = 0; m < 8; ++m)
#pragma unroll
        for (int n = 0; n < 4; ++n) acc[m][n] = zero;

    const int NT = K >> 6;     // BK=64 tiles (even for all call sites)
    const int NI = NT >> 1;

    // prologue: tile0 A+B -> b0, tile1 B -> b1; confirm tile0 (B(1) stays in flight)
    STG_A(0, 0, 0); STG_A(0, 0, 1);
    STG_B(0, 0, 0); STG_B(0, 0, 1);
    STG_B(1, 1, 0); STG_B(1, 1, 1);
    VMW(4);
    BAR();

    bf16x8 af[4], bfr[4][2];

    for (int i = 0; i < NI; ++i) {
        const int T  = 2 * i;
        const int k2 = (T + 2 < NT) ? T + 2 : NT - 1;   // clamped source (dest dead on last iter)
        const int k3 = (T + 3 < NT) ? T + 3 : NT - 1;

        // ---- tile T (buf0) ----
        STG_A(1, T + 1, 0); LD_B4(0, 0); LD_A4(0, 0, 0);
        BAR(); LGKM0(); MF(0, 0); BAR();
        STG_A(1, T + 1, 1); LD_B4(0, 1); LD_A4(0, 0, 1);
        BAR(); LGKM0(); MF(0, 1); BAR();
        STG_B(0, k2, 0);                 LD_A4(0, 1, 0);
        BAR(); LGKM0(); MF(1, 0); BAR();
        STG_B(0, k2, 1);                 LD_A4(0, 1, 1);
        BAR(); LGKM0(); MF(1, 1);
        VMW(4); BAR();                                   // tile T+1 confirmed

        // ---- tile T+1 (buf1) ----
        STG_A(0, k2, 0); LD_B4(1, 0); LD_A4(1, 0, 0);
        BAR(); LGKM0(); MF(0, 0); BAR();
        STG_A(0, k2, 1); LD_B4(1, 1); LD_A4(1, 0, 1);
        BAR(); LGKM0(); MF(0, 1); BAR();
        STG_B(1, k3, 0);              LD_A4(1, 1, 0);
        BAR(); LGKM0(); MF(1, 0); BAR();
        STG_B(1, k3, 1);              LD_A4(1, 1, 1);
        BAR(); LGKM0(); MF(1, 1);
        VMW(4); BAR();                                   // tile T+2 confirmed

        // ---- segment-boundary fold: acc *= ratT[p][row] (telescoping probs) ----
        if (((i + 1) & (TPS / 2 - 1)) == 0) {
            const int p = (i + 1) / (TPS / 2) - 1;       // 0..7
            const float* rp = ratT + (size_t)p * B_SZ + (m0 + wr * 128 + quad * 4);
            f32x4 rr[8];
#pragma unroll
            for (int m = 0; m < 8; ++m) rr[m] = *(const f32x4*)(rp + m * 16);
#pragma unroll
            for (int m = 0; m < 8; ++m)
#pragma unroll
                for (int n = 0; n < 4; ++n)
                    acc[m][n] *= rr[m];
        }
    }

    asm volatile("s_waitcnt vmcnt(0)" ::: "memory");  // drain trailing (dead) stages

    // epilogue: + Σ_p probs·bexp[p,:], ReLU, bf16 store
    const int colb = n0 + wc * 64 + l16;
    float bx[4][NP];
#pragma unroll
    for (int n = 0; n < 4; ++n)
#pragma unroll
        for (int p = 0; p < NP; ++p)
            bx[n][p] = bexp[(size_t)p * N + colb + n * 16];
#pragma unroll
    for (int m = 0; m < 8; ++m) {
#pragma unroll
        for (int r = 0; r < 4; ++r) {
            const int row = m0 + wr * 128 + m * 16 + quad * 4 + r;
            const float* pr = probs + (size_t)row * NP;
            f32x4 p0 = *(const f32x4*)pr;
            f32x4 p1 = *(const f32x4*)(pr + 4);
            float pv[NP] = {p0[0], p0[1], p0[2], p0[3], p1[0], p1[1], p1[2], p1[3]};
#pragma unroll
            for (int n = 0; n < 4; ++n) {
                float bsum = 0.f;
#pragma unroll
                for (int p = 0; p < NP; ++p) bsum += pv[p] * bx[n][p];
                float v = fmaxf(acc[m][n][r] + bsum, 0.f);
                C[(size_t)row * N + colb + n * 16] = __float2bfloat16(v);
            }
        }
    }
#undef STG_A
#undef STG_B
#undef LD_A4
#undef LD_B4
#undef BAR
#undef LGKM0
#undef VMW
#undef MF
}

// Plain C = A @ Bt^T + bias (f32 out) for the classifier. 128x128, dbuf, swizzled.
__global__ __launch_bounds__(256)
void gemm_bt_k(const __hip_bfloat16* __restrict__ A, const __hip_bfloat16* __restrict__ Bt,
               int M, int N, int K, const float* __restrict__ bias, float* __restrict__ C) {
    __shared__ alignas(16) __hip_bfloat16 As[2 * 128 * 32];
    __shared__ alignas(16) __hip_bfloat16 Bs[2 * 128 * 32];
    const int tid  = threadIdx.x;
    const int wid  = tid >> 6, lane = tid & 63;
    const int quad = lane >> 4, l16 = lane & 15;
    const int waveM = (wid >> 1) << 6, waveN = (wid & 1) << 6;
    const int m0 = blockIdx.x * 128, n0 = blockIdx.y * 128;

    f32x4 zero = {0.f, 0.f, 0.f, 0.f};
    f32x4 acc[4][4];
#pragma unroll
    for (int a = 0; a < 4; ++a)
#pragma unroll
        for (int b = 0; b < 4; ++b) acc[a][b] = zero;

    const int srow = tid >> 2;
    const int skc  = (((tid & 3) ^ (srow & 3) ^ ((srow >> 2) & 3)) << 3);
    const __hip_bfloat16* Ag = A  + (size_t)(m0 + srow) * K + skc;
    const __hip_bfloat16* Bg = Bt + (size_t)(n0 + srow) * K + skc;
    const size_t rowStep = (size_t)64 * K;
    __hip_bfloat16* AsB = As + wid * 512;
    __hip_bfloat16* BsB = Bs + wid * 512;
    const int csel = (quad ^ (l16 & 3) ^ ((l16 >> 2) & 3)) << 3;

    async_ld16(Ag,           AsB);
    async_ld16(Ag + rowStep, AsB + 2048);
    async_ld16(Bg,           BsB);
    async_ld16(Bg + rowStep, BsB + 2048);

    for (int kt = 0; kt < K; kt += 32) {
        const int cur = (kt >> 5) & 1;
        __syncthreads();
        if (kt + 32 < K) {
            const int nb = (1 - cur) * 4096;
            async_ld16(Ag + kt + 32,           AsB + nb);
            async_ld16(Ag + kt + 32 + rowStep, AsB + nb + 2048);
            async_ld16(Bg + kt + 32,           BsB + nb);
            async_ld16(Bg + kt + 32 + rowStep, BsB + nb + 2048);
        }
        const __hip_bfloat16* AsC = As + cur * 4096;
        const __hip_bfloat16* BsC = Bs + cur * 4096;
        bf16x8 af[4], bfr[4];
#pragma unroll
        for (int q = 0; q < 4; ++q) {
            af[q]  = *(const bf16x8*)(AsC + (waveM + q * 16 + l16) * 32 + csel);
            bfr[q] = *(const bf16x8*)(BsC + (waveN + q * 16 + l16) * 32 + csel);
        }
#pragma unroll
        for (int tm = 0; tm < 4; ++tm)
#pragma unroll
            for (int tn = 0; tn < 4; ++tn)
                acc[tm][tn] = __builtin_amdgcn_mfma_f32_16x16x32_bf16(
                    af[tm], bfr[tn], acc[tm][tn], 0, 0, 0);
    }

    const int colb = n0 + waveN + l16;
#pragma unroll
    for (int tm = 0; tm < 4; ++tm)
#pragma unroll
        for (int r = 0; r < 4; ++r) {
            int row = m0 + waveM + tm * 16 + quad * 4 + r;
#pragma unroll
            for (int tn = 0; tn < 4; ++tn)
                C[(size_t)row * N + colb + tn * 16] =
                    acc[tm][tn][r] + bias[colb + tn * 16];
        }
}

extern "C" void kernel_launch(void* const* d_in, const int* in_sizes, int n_in,
                              void* d_out, int out_size, void* d_ws, size_t ws_size,
                              hipStream_t stream) {
    const float* x   = (const float*)d_in[0];
    const float* W1  = (const float*)d_in[1];
    const float* b1  = (const float*)d_in[2];
    const float* S1  = (const float*)d_in[3];
    const float* sb1 = (const float*)d_in[4];
    const float* W2  = (const float*)d_in[5];
    const float* b2  = (const float*)d_in[6];
    const float* S2  = (const float*)d_in[7];
    const float* sb2 = (const float*)d_in[8];
    const float* Wc  = (const float*)d_in[9];
    const float* bc  = (const float*)d_in[10];
    float* out = (float*)d_out;

    char* ws = (char*)d_ws;
    size_t off = 0;
    auto alloc = [&](size_t bytes) {
        char* p = ws + off;
        off += (bytes + 255) & ~(size_t)255;
        return p;
    };
    __hip_bfloat16* W1t = (__hip_bfloat16*)alloc((size_t)H1_SZ * (NP * IN_SZ) * 2);  // 32 MB
    __hip_bfloat16* W2t = (__hip_bfloat16*)alloc((size_t)H2_SZ * (NP * H1_SZ) * 2);  // 64 MB
    __hip_bfloat16* Wct = (__hip_bfloat16*)alloc((size_t)OUT_SZ * H2_SZ * 2);        //  4 MB
    float* probs1       = (float*)alloc((size_t)B_SZ * NP * 4);
    float* probs2       = (float*)alloc((size_t)B_SZ * NP * 4);
    float* rat1         = (float*)alloc((size_t)NP * B_SZ * 4);
    float* rat2         = (float*)alloc((size_t)NP * B_SZ * 4);
    __hip_bfloat16* xbf = (__hip_bfloat16*)alloc((size_t)B_SZ * IN_SZ * 2);          // 16 MB
    __hip_bfloat16* h1  = (__hip_bfloat16*)alloc((size_t)B_SZ * H1_SZ * 2);          // 32 MB
    __hip_bfloat16* h2  = (__hip_bfloat16*)alloc((size_t)B_SZ * H2_SZ * 2);          // 32 MB

    // unified prep: W1t + W2t + Wct transposes + x cast in one dispatch
    const int nPrep = (H1_SZ / 32) * ((NP * IN_SZ) / 32)
                    + (H2_SZ / 32) * ((NP * H1_SZ) / 32)
                    + (OUT_SZ / 32) * (H2_SZ / 32)
                    + (B_SZ * IN_SZ) / (256 * 8);
    prep_k<<<nPrep, dim3(32, 8), 0, stream>>>(W1, W2, Wc, x, W1t, W2t, Wct, xbf);

    // layer 1 (TPS = IN/64 = 16)
    selector_k<float><<<B_SZ / 4, dim3(64, 4), 0, stream>>>(x, S1, sb1, probs1, rat1, IN_SZ);
    drn_gemm8_k<16><<<(B_SZ / 256) * (H1_SZ / 256), 512, 0, stream>>>(
        xbf, W1t, H1_SZ, NP * IN_SZ, IN_SZ, rat1, probs1, b1, h1);

    // layer 2 (TPS = H1/64 = 32)
    selector_k<__hip_bfloat16><<<B_SZ / 4, dim3(64, 4), 0, stream>>>(h1, S2, sb2, probs2, rat2, H1_SZ);
    drn_gemm8_k<32><<<(B_SZ / 256) * (H2_SZ / 256), 512, 0, stream>>>(
        h1, W2t, H2_SZ, NP * H1_SZ, H1_SZ, rat2, probs2, b2, h2);

    // classifier
    gemm_bt_k<<<dim3(B_SZ / 128, OUT_SZ / 128), 256, 0, stream>>>(
        h2, Wct, B_SZ, OUT_SZ, H2_SZ, bc, out);
}